// Round 3
// baseline (2191.510 us; speedup 1.0000x reference)
//
#include <hip/hip_runtime.h>
#include <math.h>

typedef unsigned int u32;
typedef unsigned long long u64;
typedef __attribute__((ext_vector_type(8))) short bf16x8;   // 8 bf16 = 4 VGPR
typedef __attribute__((ext_vector_type(4))) float f32x4;

#define TT 256

// ---- ws byte offsets ----
#define BOFF_WT   0ULL          // bf16 [3 mat][2 pl][8 kc][1024 n][40 kpad] = 3,932,160 B
#define BOFF_WX   3932160ULL    // fp32 [10][1024] = 40,960 B
#define BOFF_H0HI 3973120ULL    // bf16 [2 slot][8 ib][32 ik][64 r][8 u] = 524,288 B each
#define BOFF_H0LO 4497408ULL
#define BOFF_H1HI 5021696ULL
#define BOFF_H1LO 5545984ULL
#define BOFF_FLG  6070272ULL    // u32 [(e*8+ib)*16], 257*8*16*4 = 131,584 B

// ---------------------------------------------------------------------------
// W [1024][K] row-major -> A [K][1024] gate-interleaved fp32 (for x-gemm)
__global__ void transpose_gi(const float* __restrict__ W, float* __restrict__ A, int K) {
    int idx = blockIdx.x * 256 + threadIdx.x;
    if (idx < K * 1024) {
        int kk = idx >> 10, r = idx & 1023, k = r >> 2, g = r & 3;
        A[idx] = W[(g * 256 + k) * K + kk];
    }
}

// Split fp32 weights into hi/lo bf16 planes, MFMA B-tile layout:
// wt[((mt*2+pl)*8 + kc)*1024 + n][40] , n = gate-col (u*4+g), k within chunk 0..31
__global__ void split_w(const float* __restrict__ W0, const float* __restrict__ W1,
                        const float* __restrict__ W2, unsigned short* __restrict__ wt) {
    int idx = blockIdx.x * 256 + threadIdx.x;      // 786432 total
    int k32 = idx & 31;
    int n   = (idx >> 5) & 1023;
    int kc  = (idx >> 15) & 7;
    int mt  = idx >> 18;
    const float* W = (mt == 0) ? W0 : (mt == 1) ? W1 : W2;
    int ug = n >> 2, g = n & 3, k = kc * 32 + k32;
    float v = W[(g * 256 + ug) * 256 + k];
    u32 b = __float_as_uint(v);
    unsigned short hi = (unsigned short)(b >> 16);               // truncated hi
    float lo = v - __uint_as_float(b & 0xFFFF0000u);             // exact residual
    u32 lb = __float_as_uint(lo);
    unsigned short los = (unsigned short)((lb + 0x7FFFu + ((lb >> 16) & 1u)) >> 16);
    wt[((size_t)((mt * 2 + 0) * 8 + kc) * 1024 + n) * 40 + k32] = hi;
    wt[((size_t)((mt * 2 + 1) * 8 + kc) * 1024 + n) * 40 + k32] = los;
}

__device__ __forceinline__ float sigf(float x)     { return 1.0f / (1.0f + __expf(-x)); }
__device__ __forceinline__ float tanhfast(float x) { return 1.0f - 2.0f / (__expf(2.0f * x) + 1.0f); }

__device__ __forceinline__ u64 ldg8(const unsigned short* p) {
    return __hip_atomic_load((const u64*)(const void*)p, __ATOMIC_RELAXED, __HIP_MEMORY_SCOPE_AGENT);
}
__device__ __forceinline__ u32 ldg4(const unsigned short* p) {
    return __hip_atomic_load((const u32*)(const void*)p, __ATOMIC_RELAXED, __HIP_MEMORY_SCOPE_AGENT);
}
__device__ __forceinline__ void stg4(unsigned short* p, u32 v) {
    __hip_atomic_store((u32*)(void*)p, v, __ATOMIC_RELAXED, __HIP_MEMORY_SCOPE_AGENT);
}
__device__ __forceinline__ unsigned short bhi(float v) {
    return (unsigned short)(__float_as_uint(v) >> 16);
}
__device__ __forceinline__ unsigned short blo(float v) {
    float lo = v - __uint_as_float(__float_as_uint(v) & 0xFFFF0000u);
    u32 lb = __float_as_uint(lo);
    return (unsigned short)((lb + 0x7FFFu + ((lb >> 16) & 1u)) >> 16);
}
__device__ __forceinline__ float bff(u32 us) { return __uint_as_float(us << 16); }

union FragU { u64 q[2]; bf16x8 v; };

// ---------------------------------------------------------------------------
// MFMA persistent 2-layer LSTM. 256 blocks (1/CU) x 256 threads (4 waves).
// Block (ib,ik): 64 batch rows x 8 hidden units (32 gate cols). Weights in LDS
// as bf16 hi/lo B-tiles. h ring in IF$, block-tile-major [slot][ib][ik][r][u].
// Wave (rh,ch): rows rh*32..+32 (2 A-tiles), cols ch*16..+16 (1 B-tile).
// This rev: 4-deep A-chunk prefetch (chunks 0..3 issued right after the flag
// wait, before the xc VALU block) to cover the ~600-900cy MALL latency of the
// agent-scope h-ring loads; one merged __syncthreads per step.
// ---------------------------------------------------------------------------
__global__ __launch_bounds__(256, 1)
void lstm_mfma(const float* __restrict__ x,
               const float* __restrict__ bih0, const float* __restrict__ bhh0,
               const float* __restrict__ bih1, const float* __restrict__ bhh1,
               const float* __restrict__ Wlin, const float* __restrict__ blin,
               char* __restrict__ wsb, float* __restrict__ out)
{
    __shared__ unsigned short lw[61440];   // B-tiles: [6 pl][8 kc][32 n][40 kpad]
    __shared__ float fsh[5184];            // Wx [10][32] | xs [10][64] | CS [2][64][33]
    float* ldsWx = fsh;
    float* xs    = fsh + 320;
    float* CS    = fsh + 960;

    const int tid  = threadIdx.x;
    const int lane = tid & 63;
    const int wv   = __builtin_amdgcn_readfirstlane(tid >> 6);
    const int quad = lane >> 4;
    const int l15  = lane & 15;
    const int rh   = wv >> 1;              // row-half (32 rows)
    const int ch   = wv & 1;               // col-half (16 gate-cols)
    const int ib   = blockIdx.x & 7;
    const int ik   = blockIdx.x >> 3;
    const int rb0  = ib * 64;

    const unsigned short* wt = (const unsigned short*)(wsb + BOFF_WT);
    const float* gWx = (const float*)(wsb + BOFF_WX);
    unsigned short* h0hi = (unsigned short*)(wsb + BOFF_H0HI);
    unsigned short* h0lo = (unsigned short*)(wsb + BOFF_H0LO);
    unsigned short* h1hi = (unsigned short*)(wsb + BOFF_H1HI);
    unsigned short* h1lo = (unsigned short*)(wsb + BOFF_H1LO);
    u32* flg = (u32*)(wsb + BOFF_FLG);

    // ---- one-time: weight B-tiles (this block's 32-col slice) into LDS ----
    #pragma unroll 1
    for (int j = 0; j < 30; ++j) {
        int i16 = tid + j * 256;               // 0..7679 (b128 units)
        int chk = i16 / 160;                   // plane-chunk 0..47
        int wi  = i16 - chk * 160;             // b128 unit within chunk
        size_t src = (size_t)chk * 40960 + (size_t)ik * 1280 + (size_t)wi * 8;
        *(ulonglong2*)(lw + (size_t)chk * 1280 + (size_t)wi * 8) =
            *(const ulonglong2*)(wt + src);
    }
    for (int n = tid; n < 320; n += 256)
        ldsWx[n] = gWx[(n >> 5) * 1024 + ik * 32 + (n & 31)];

    // biases in regs (eltwise mapping: r = tid>>2, unit-pair up = tid&3)
    float b0r[8], b1r[8];
    {
        int up = tid & 3;
        #pragma unroll
        for (int j = 0; j < 8; ++j) {
            int ul = up * 2 + (j >> 2), g = j & 3;
            int gi = g * 256 + ik * 8 + ul;
            b0r[j] = bih0[gi] + bhh0[gi];
            b1r[j] = bih1[gi] + bhh1[gi];
        }
    }
    float c0s[2] = {0.f, 0.f}, c1s[2] = {0.f, 0.f};
    const int rl0 = rh * 32 + l15;          // local row, A-tile 0 (tile1 = +16)
    const bf16x8* bw = (const bf16x8*)lw;

    __syncthreads();

    for (int e = 0; e <= TT; ++e) {
        // ---- stage x[te] ----
        {
            int te = (e < TT) ? e : (TT - 1);
            #pragma unroll
            for (int rr = 0; rr < 2; ++rr) {
                int idx = tid + rr * 256;
                if (idx < 320) {
                    int r = idx / 5, j2 = idx - r * 5;
                    float2 v = *(const float2*)(x + (size_t)(rb0 + r) * 2560 + te * 10 + 2 * j2);
                    xs[(2 * j2) * 64 + r]     = v.x;
                    xs[(2 * j2 + 1) * 64 + r] = v.y;
                }
            }
        }

        // ---- wait for row-group's previous step (overlapped w/ x staging) ----
        if (e > 0) {
            if (tid == 0) {
                u32* cp = flg + ((e - 1) * 8 + ib) * 16;
                while (__hip_atomic_load(cp, __ATOMIC_RELAXED, __HIP_MEMORY_SCOPE_AGENT) < 32u)
                    __builtin_amdgcn_s_sleep(2);
            }
        }
        __syncthreads();   // covers xs visibility AND flag release

        // ---- gemm: 8 k32-chunks; A direct from IF$ tile ring, B from LDS ----
        const unsigned short* p0h = h0hi + (size_t)(((e + 1) & 1) * 8 + ib) * 16384;
        const unsigned short* p0l = h0lo + (size_t)(((e + 1) & 1) * 8 + ib) * 16384;
        const unsigned short* p1h = h1hi + (size_t)((e & 1) * 8 + ib) * 16384;
        const unsigned short* p1l = h1lo + (size_t)((e & 1) * 8 + ib) * 16384;
        const int oa0 = quad * 512 + rl0 * 8;          // A-tile0 lane offset
        const int oa1 = oa0 + 16 * 8;                  // A-tile1 (+16 rows)

        u64 bA[4][16];
        #define ISSUE_A(b, qc) { int tb = (qc) * 2048;                              \
            bA[b][0]  = ldg8(p0h + tb + oa0); bA[b][1]  = ldg8(p0h + tb + oa0 + 4); \
            bA[b][2]  = ldg8(p0l + tb + oa0); bA[b][3]  = ldg8(p0l + tb + oa0 + 4); \
            bA[b][4]  = ldg8(p1h + tb + oa0); bA[b][5]  = ldg8(p1h + tb + oa0 + 4); \
            bA[b][6]  = ldg8(p1l + tb + oa0); bA[b][7]  = ldg8(p1l + tb + oa0 + 4); \
            bA[b][8]  = ldg8(p0h + tb + oa1); bA[b][9]  = ldg8(p0h + tb + oa1 + 4); \
            bA[b][10] = ldg8(p0l + tb + oa1); bA[b][11] = ldg8(p0l + tb + oa1 + 4); \
            bA[b][12] = ldg8(p1h + tb + oa1); bA[b][13] = ldg8(p1h + tb + oa1 + 4); \
            bA[b][14] = ldg8(p1l + tb + oa1); bA[b][15] = ldg8(p1l + tb + oa1 + 4); }
        // 4-deep prefetch: fill the pipe before any compute
        ISSUE_A(0, 0)
        ISSUE_A(1, 1)
        ISSUE_A(2, 2)
        ISSUE_A(3, 3)

        // ---- x contribution + bias (VALU work covers A-load latency) ----
        float xc[8];
        {
            int r = tid >> 2, up = tid & 3;
            #pragma unroll
            for (int j = 0; j < 8; ++j) xc[j] = b0r[j];
            #pragma unroll
            for (int i = 0; i < 10; ++i) {
                float xv = xs[i * 64 + r];
                #pragma unroll
                for (int j = 0; j < 8; ++j)
                    xc[j] += xv * ldsWx[i * 32 + up * 8 + j];
            }
        }

        f32x4 C0[2], C1[2];
        #pragma unroll
        for (int rt = 0; rt < 2; ++rt) {
            C0[rt] = (f32x4){0.f, 0.f, 0.f, 0.f};
            C1[rt] = (f32x4){0.f, 0.f, 0.f, 0.f};
        }

        #pragma unroll
        for (int q = 0; q < 8; ++q) {
            const int b = q & 3;
            const int rbase = ch * 16 + l15;
            bf16x8 wah = bw[5 * ((0 * 8 + q) * 32 + rbase) + quad];  // hh0 hi
            bf16x8 wal = bw[5 * ((1 * 8 + q) * 32 + rbase) + quad];  // hh0 lo
            bf16x8 wbh = bw[5 * ((2 * 8 + q) * 32 + rbase) + quad];  // ih1 hi
            bf16x8 wbl = bw[5 * ((3 * 8 + q) * 32 + rbase) + quad];  // ih1 lo
            bf16x8 wch = bw[5 * ((4 * 8 + q) * 32 + rbase) + quad];  // hh1 hi
            bf16x8 wcl = bw[5 * ((5 * 8 + q) * 32 + rbase) + quad];  // hh1 lo
            FragU a0h, a0l, a1h, a1l;
            #pragma unroll
            for (int rt = 0; rt < 2; ++rt) {
                a0h.q[0] = bA[b][rt*8+0];  a0h.q[1] = bA[b][rt*8+1];
                a0l.q[0] = bA[b][rt*8+2];  a0l.q[1] = bA[b][rt*8+3];
                a1h.q[0] = bA[b][rt*8+4];  a1h.q[1] = bA[b][rt*8+5];
                a1l.q[0] = bA[b][rt*8+6];  a1l.q[1] = bA[b][rt*8+7];
                C0[rt] = __builtin_amdgcn_mfma_f32_16x16x32_bf16(a0h.v, wah, C0[rt], 0, 0, 0);
                C0[rt] = __builtin_amdgcn_mfma_f32_16x16x32_bf16(a0h.v, wal, C0[rt], 0, 0, 0);
                C0[rt] = __builtin_amdgcn_mfma_f32_16x16x32_bf16(a0l.v, wah, C0[rt], 0, 0, 0);
                C0[rt] = __builtin_amdgcn_mfma_f32_16x16x32_bf16(a0l.v, wal, C0[rt], 0, 0, 0);
                C1[rt] = __builtin_amdgcn_mfma_f32_16x16x32_bf16(a0h.v, wbh, C1[rt], 0, 0, 0);
                C1[rt] = __builtin_amdgcn_mfma_f32_16x16x32_bf16(a0h.v, wbl, C1[rt], 0, 0, 0);
                C1[rt] = __builtin_amdgcn_mfma_f32_16x16x32_bf16(a0l.v, wbh, C1[rt], 0, 0, 0);
                C1[rt] = __builtin_amdgcn_mfma_f32_16x16x32_bf16(a0l.v, wbl, C1[rt], 0, 0, 0);
                C1[rt] = __builtin_amdgcn_mfma_f32_16x16x32_bf16(a1h.v, wch, C1[rt], 0, 0, 0);
                C1[rt] = __builtin_amdgcn_mfma_f32_16x16x32_bf16(a1h.v, wcl, C1[rt], 0, 0, 0);
                C1[rt] = __builtin_amdgcn_mfma_f32_16x16x32_bf16(a1l.v, wch, C1[rt], 0, 0, 0);
                C1[rt] = __builtin_amdgcn_mfma_f32_16x16x32_bf16(a1l.v, wcl, C1[rt], 0, 0, 0);
            }
            if (q < 4) ISSUE_A(b, q + 4)
        }
        #undef ISSUE_A

        // ---- C/D frags -> scratch (D: col=lane&15, row=quad*4+reg) ----
        #pragma unroll
        for (int rt = 0; rt < 2; ++rt)
            #pragma unroll
            for (int reg = 0; reg < 4; ++reg) {
                int rr = rh * 32 + rt * 16 + quad * 4 + reg;
                CS[rr * 33 + ch * 16 + l15]        = C0[rt][reg];
                CS[2112 + rr * 33 + ch * 16 + l15] = C1[rt][reg];
            }
        __syncthreads();

        // ---- eltwise (thread = row x unit-pair); pack + tile-contiguous store ----
        {
            int r = tid >> 2, up = tid & 3;
            if (e < TT) {
                float h0n[2];
                #pragma unroll
                for (int s = 0; s < 2; ++s) {
                    int c4 = up * 8 + s * 4;
                    float gi = CS[r * 33 + c4 + 0] + xc[s * 4 + 0];
                    float gf = CS[r * 33 + c4 + 1] + xc[s * 4 + 1];
                    float gg = CS[r * 33 + c4 + 2] + xc[s * 4 + 2];
                    float go = CS[r * 33 + c4 + 3] + xc[s * 4 + 3];
                    float cn = sigf(gf) * c0s[s] + sigf(gi) * tanhfast(gg);
                    c0s[s] = cn;
                    h0n[s] = sigf(go) * tanhfast(cn);
                }
                size_t tb = (size_t)((e & 1) * 8 + ib) * 16384 + (size_t)ik * 512 + 2 * tid;
                stg4(h0hi + tb, (u32)bhi(h0n[0]) | ((u32)bhi(h0n[1]) << 16));
                stg4(h0lo + tb, (u32)blo(h0n[0]) | ((u32)blo(h0n[1]) << 16));
            }
            if (e > 0) {
                float h1n[2];
                #pragma unroll
                for (int s = 0; s < 2; ++s) {
                    int c4 = up * 8 + s * 4;
                    float gi = CS[2112 + r * 33 + c4 + 0] + b1r[s * 4 + 0];
                    float gf = CS[2112 + r * 33 + c4 + 1] + b1r[s * 4 + 1];
                    float gg = CS[2112 + r * 33 + c4 + 2] + b1r[s * 4 + 2];
                    float go = CS[2112 + r * 33 + c4 + 3] + b1r[s * 4 + 3];
                    float cn = sigf(gf) * c1s[s] + sigf(gi) * tanhfast(gg);
                    c1s[s] = cn;
                    h1n[s] = sigf(go) * tanhfast(cn);
                }
                size_t tb = (size_t)(((e + 1) & 1) * 8 + ib) * 16384 + (size_t)ik * 512 + 2 * tid;
                stg4(h1hi + tb, (u32)bhi(h1n[0]) | ((u32)bhi(h1n[1]) << 16));
                stg4(h1lo + tb, (u32)blo(h1n[0]) | ((u32)blo(h1n[1]) << 16));
            }
        }
        asm volatile("s_waitcnt vmcnt(0)" ::: "memory");
        __syncthreads();
        if (tid == 0)
            __hip_atomic_fetch_add(flg + (e * 8 + ib) * 16, 1u,
                                   __ATOMIC_RELAXED, __HIP_MEMORY_SCOPE_AGENT);
    }

    // ---- head: y[b] = h1[255] . Wlin + blin (slot 1, tile layout) ----
    if (ik == 0) {
        if (tid == 0) {
            u32* cp = flg + (TT * 8 + ib) * 16;
            while (__hip_atomic_load(cp, __ATOMIC_RELAXED, __HIP_MEMORY_SCOPE_AGENT) < 32u)
                __builtin_amdgcn_s_sleep(2);
        }
        __syncthreads();
        int r = tid >> 2, q4 = tid & 3;
        const unsigned short* ph = h1hi + (size_t)(1 * 8 + ib) * 16384;
        const unsigned short* pl = h1lo + (size_t)(1 * 8 + ib) * 16384;
        float sacc = 0.f;
        #pragma unroll 1
        for (int kk = 0; kk < 64; kk += 2) {
            int k = q4 * 64 + kk;
            int sa = (k >> 3) * 512 + r * 8 + (k & 7);
            u32 hw = ldg4(ph + sa), lwd = ldg4(pl + sa);
            sacc += (bff(hw & 0xFFFFu) + bff(lwd & 0xFFFFu)) * Wlin[k];
            sacc += (bff(hw >> 16)     + bff(lwd >> 16))     * Wlin[k + 1];
        }
        sacc += __shfl_down(sacc, 2, 4);
        sacc += __shfl_down(sacc, 1, 4);
        if (q4 == 0) out[rb0 + r] = sacc + blin[0];
    }
}

// ---------------------------------------------------------------------------
extern "C" void kernel_launch(void* const* d_in, const int* in_sizes, int n_in,
                              void* d_out, int out_size, void* d_ws, size_t ws_size,
                              hipStream_t stream) {
    const float* x     = (const float*)d_in[0];
    const float* W_ih0 = (const float*)d_in[1];
    const float* W_hh0 = (const float*)d_in[2];
    const float* b_ih0 = (const float*)d_in[3];
    const float* b_hh0 = (const float*)d_in[4];
    const float* W_ih1 = (const float*)d_in[5];
    const float* W_hh1 = (const float*)d_in[6];
    const float* b_ih1 = (const float*)d_in[7];
    const float* b_hh1 = (const float*)d_in[8];
    const float* W_lin = (const float*)d_in[9];
    const float* b_lin = (const float*)d_in[10];
    float* out = (float*)d_out;
    char* wsb  = (char*)d_ws;

    // zero h ring planes + flags (ws re-poisoned before every timed launch)
    hipMemsetAsync(wsb + BOFF_H0HI, 0, 4 * 524288 + 131584, stream);

    split_w<<<3072, 256, 0, stream>>>(W_hh0, W_ih1, W_hh1,
                                      (unsigned short*)(wsb + BOFF_WT));
    transpose_gi<<<40, 256, 0, stream>>>(W_ih0, (float*)(wsb + BOFF_WX), 10);

    lstm_mfma<<<256, 256, 0, stream>>>(x, b_ih0, b_hh0, b_ih1, b_hh1,
                                       W_lin, b_lin, wsb, out);
}

// Round 4
// 2043.831 us; speedup vs baseline: 1.0723x; 1.0723x over previous
//
#include <hip/hip_runtime.h>
#include <math.h>

typedef unsigned int u32;
typedef unsigned long long u64;
typedef __attribute__((ext_vector_type(8))) short bf16x8;   // 8 bf16 = 4 VGPR
typedef __attribute__((ext_vector_type(4))) float f32x4;

#define TT 256

// ---- ws byte offsets ----
#define BOFF_WT   0ULL          // bf16 [3 mat][2 pl][8 kc][1024 n][40 kpad] = 3,932,160 B
#define BOFF_WX   3932160ULL    // fp32 [10][1024] = 40,960 B
#define BOFF_H0HI 3973120ULL    // bf16 [2 slot][8 ib][32 ik][64 r][8 u] = 524,288 B each
#define BOFF_H0LO 4497408ULL
#define BOFF_H1HI 5021696ULL
#define BOFF_H1LO 5545984ULL
#define BOFF_FLG  6070272ULL    // u32 flag[ib][32], one 128B line per ib (monotonic)

// ---------------------------------------------------------------------------
// W [1024][K] row-major -> A [K][1024] gate-interleaved fp32 (for x-gemm)
__global__ void transpose_gi(const float* __restrict__ W, float* __restrict__ A, int K) {
    int idx = blockIdx.x * 256 + threadIdx.x;
    if (idx < K * 1024) {
        int kk = idx >> 10, r = idx & 1023, k = r >> 2, g = r & 3;
        A[idx] = W[(g * 256 + k) * K + kk];
    }
}

// Split fp32 weights into hi/lo bf16 planes, MFMA B-tile layout:
// wt[((mt*2+pl)*8 + kc)*1024 + n][40] , n = gate-col (u*4+g), k within chunk 0..31
__global__ void split_w(const float* __restrict__ W0, const float* __restrict__ W1,
                        const float* __restrict__ W2, unsigned short* __restrict__ wt) {
    int idx = blockIdx.x * 256 + threadIdx.x;      // 786432 total
    int k32 = idx & 31;
    int n   = (idx >> 5) & 1023;
    int kc  = (idx >> 15) & 7;
    int mt  = idx >> 18;
    const float* W = (mt == 0) ? W0 : (mt == 1) ? W1 : W2;
    int ug = n >> 2, g = n & 3, k = kc * 32 + k32;
    float v = W[(g * 256 + ug) * 256 + k];
    u32 b = __float_as_uint(v);
    unsigned short hi = (unsigned short)(b >> 16);               // truncated hi
    float lo = v - __uint_as_float(b & 0xFFFF0000u);             // exact residual
    u32 lb = __float_as_uint(lo);
    unsigned short los = (unsigned short)((lb + 0x7FFFu + ((lb >> 16) & 1u)) >> 16);
    wt[((size_t)((mt * 2 + 0) * 8 + kc) * 1024 + n) * 40 + k32] = hi;
    wt[((size_t)((mt * 2 + 1) * 8 + kc) * 1024 + n) * 40 + k32] = los;
}

__device__ __forceinline__ float sigf(float x)     { return 1.0f / (1.0f + __expf(-x)); }
__device__ __forceinline__ float tanhfast(float x) { return 1.0f - 2.0f / (__expf(2.0f * x) + 1.0f); }

__device__ __forceinline__ u64 ldg8(const unsigned short* p) {
    return __hip_atomic_load((const u64*)(const void*)p, __ATOMIC_RELAXED, __HIP_MEMORY_SCOPE_AGENT);
}
__device__ __forceinline__ u32 ldg4(const unsigned short* p) {
    return __hip_atomic_load((const u32*)(const void*)p, __ATOMIC_RELAXED, __HIP_MEMORY_SCOPE_AGENT);
}
__device__ __forceinline__ void stg4(unsigned short* p, u32 v) {
    __hip_atomic_store((u32*)(void*)p, v, __ATOMIC_RELAXED, __HIP_MEMORY_SCOPE_AGENT);
}
__device__ __forceinline__ unsigned short bhi(float v) {
    return (unsigned short)(__float_as_uint(v) >> 16);
}
__device__ __forceinline__ unsigned short blo(float v) {
    float lo = v - __uint_as_float(__float_as_uint(v) & 0xFFFF0000u);
    u32 lb = __float_as_uint(lo);
    return (unsigned short)((lb + 0x7FFFu + ((lb >> 16) & 1u)) >> 16);
}
__device__ __forceinline__ float bff(u32 us) { return __uint_as_float(us << 16); }

// Per-producer readiness snapshot: lane p (p=lane&31) loads flag word p of this
// ib-group's 128B flag line; ballot -> bit p set iff producer p stored >= tgt.
__device__ __forceinline__ u32 mkrdy(const u32* fl, int lane, u32 tgt) {
    u32 v = __hip_atomic_load(fl + (lane & 31), __ATOMIC_RELAXED,
                              __HIP_MEMORY_SCOPE_AGENT);
    unsigned long long b = __ballot(v >= tgt);
    return (u32)b;
}

union FragU { u64 q[2]; bf16x8 v; };

// ---------------------------------------------------------------------------
// MFMA persistent 2-layer LSTM. 256 blocks (1/CU) x 256 threads (4 waves).
// Block (ib,ik): 64 batch rows x 8 hidden units (32 gate cols). Weights in LDS
// as bf16 hi/lo B-tiles. h ring in IF$, block-tile-major [slot][ib][ik][r][u].
// Wave (rh,ch): rows rh*32..+32 (2 A-tiles), cols ch*16..+16 (1 B-tile).
// This rev: PER-PRODUCER monotonic flags (32 words, one line per ib) with
// per-chunk gating — chunk q waits only on its 4 producers (ik'=4q..4q+3)
// instead of a full 32-block barrier; waves poll autonomously (no tid0
// broadcast). Chunk order 0..7 preserved -> bit-identical accumulation.
// Write-after-read safety: a block stores step s only after its gemm checked
// flags >= s-1 for ALL 32 producers (chunks 0..7 cover all), so every group
// member has finished reading the slot being overwritten.
// ---------------------------------------------------------------------------
__global__ __launch_bounds__(256, 1)
void lstm_mfma(const float* __restrict__ x,
               const float* __restrict__ bih0, const float* __restrict__ bhh0,
               const float* __restrict__ bih1, const float* __restrict__ bhh1,
               const float* __restrict__ Wlin, const float* __restrict__ blin,
               char* __restrict__ wsb, float* __restrict__ out)
{
    __shared__ unsigned short lw[61440];   // B-tiles: [6 pl][8 kc][32 n][40 kpad]
    __shared__ float fsh[5184];            // Wx [10][32] | xs [10][64] | CS [2][64][33]
    float* ldsWx = fsh;
    float* xs    = fsh + 320;
    float* CS    = fsh + 960;

    const int tid  = threadIdx.x;
    const int lane = tid & 63;
    const int wv   = __builtin_amdgcn_readfirstlane(tid >> 6);
    const int quad = lane >> 4;
    const int l15  = lane & 15;
    const int rh   = wv >> 1;              // row-half (32 rows)
    const int ch   = wv & 1;               // col-half (16 gate-cols)
    const int ib   = blockIdx.x & 7;
    const int ik   = blockIdx.x >> 3;
    const int rb0  = ib * 64;

    const unsigned short* wt = (const unsigned short*)(wsb + BOFF_WT);
    const float* gWx = (const float*)(wsb + BOFF_WX);
    unsigned short* h0hi = (unsigned short*)(wsb + BOFF_H0HI);
    unsigned short* h0lo = (unsigned short*)(wsb + BOFF_H0LO);
    unsigned short* h1hi = (unsigned short*)(wsb + BOFF_H1HI);
    unsigned short* h1lo = (unsigned short*)(wsb + BOFF_H1LO);
    const u32* fl = (const u32*)(wsb + BOFF_FLG) + ib * 32;   // this group's line
    u32* flw      = (u32*)(wsb + BOFF_FLG) + ib * 32 + ik;    // my flag word

    // ---- one-time: weight B-tiles (this block's 32-col slice) into LDS ----
    #pragma unroll 1
    for (int j = 0; j < 30; ++j) {
        int i16 = tid + j * 256;               // 0..7679 (b128 units)
        int chk = i16 / 160;                   // plane-chunk 0..47
        int wi  = i16 - chk * 160;             // b128 unit within chunk
        size_t src = (size_t)chk * 40960 + (size_t)ik * 1280 + (size_t)wi * 8;
        *(ulonglong2*)(lw + (size_t)chk * 1280 + (size_t)wi * 8) =
            *(const ulonglong2*)(wt + src);
    }
    for (int n = tid; n < 320; n += 256)
        ldsWx[n] = gWx[(n >> 5) * 1024 + ik * 32 + (n & 31)];

    // biases in regs (eltwise mapping: r = tid>>2, unit-pair up = tid&3)
    float b0r[8], b1r[8];
    {
        int up = tid & 3;
        #pragma unroll
        for (int j = 0; j < 8; ++j) {
            int ul = up * 2 + (j >> 2), g = j & 3;
            int gi = g * 256 + ik * 8 + ul;
            b0r[j] = bih0[gi] + bhh0[gi];
            b1r[j] = bih1[gi] + bhh1[gi];
        }
    }
    float c0s[2] = {0.f, 0.f}, c1s[2] = {0.f, 0.f};
    const int rl0 = rh * 32 + l15;          // local row, A-tile 0 (tile1 = +16)
    const bf16x8* bw = (const bf16x8*)lw;

    __syncthreads();

    for (int e = 0; e <= TT; ++e) {
        // ---- stage x[te] ----
        {
            int te = (e < TT) ? e : (TT - 1);
            #pragma unroll
            for (int rr = 0; rr < 2; ++rr) {
                int idx = tid + rr * 256;
                if (idx < 320) {
                    int r = idx / 5, j2 = idx - r * 5;
                    float2 v = *(const float2*)(x + (size_t)(rb0 + r) * 2560 + te * 10 + 2 * j2);
                    xs[(2 * j2) * 64 + r]     = v.x;
                    xs[(2 * j2 + 1) * 64 + r] = v.y;
                }
            }
        }
        __syncthreads();   // xs visible

        // ---- gemm: 8 k32-chunks; A direct from IF$ tile ring, B from LDS ----
        const unsigned short* p0h = h0hi + (size_t)(((e + 1) & 1) * 8 + ib) * 16384;
        const unsigned short* p0l = h0lo + (size_t)(((e + 1) & 1) * 8 + ib) * 16384;
        const unsigned short* p1h = h1hi + (size_t)((e & 1) * 8 + ib) * 16384;
        const unsigned short* p1l = h1lo + (size_t)((e & 1) * 8 + ib) * 16384;
        const int oa0 = quad * 512 + rl0 * 8;          // A-tile0 lane offset
        const int oa1 = oa0 + 16 * 8;                  // A-tile1 (+16 rows)

        // per-chunk gate: chunk q needs producers 4q..4q+3 at flag >= e
        u32 rdy = mkrdy(fl, lane, (u32)e);
        #define WCHUNK(qq) do {                                             \
            while (((rdy >> ((qq) * 4)) & 15u) != 15u) {                    \
                __builtin_amdgcn_s_sleep(1);                                \
                rdy = mkrdy(fl, lane, (u32)e);                              \
            }                                                               \
            __builtin_amdgcn_sched_barrier(0);                              \
        } while (0)

        u64 bA[2][16];
        #define ISSUE_A(b, qc) { int tb = (qc) * 2048;                              \
            bA[b][0]  = ldg8(p0h + tb + oa0); bA[b][1]  = ldg8(p0h + tb + oa0 + 4); \
            bA[b][2]  = ldg8(p0l + tb + oa0); bA[b][3]  = ldg8(p0l + tb + oa0 + 4); \
            bA[b][4]  = ldg8(p1h + tb + oa0); bA[b][5]  = ldg8(p1h + tb + oa0 + 4); \
            bA[b][6]  = ldg8(p1l + tb + oa0); bA[b][7]  = ldg8(p1l + tb + oa0 + 4); \
            bA[b][8]  = ldg8(p0h + tb + oa1); bA[b][9]  = ldg8(p0h + tb + oa1 + 4); \
            bA[b][10] = ldg8(p0l + tb + oa1); bA[b][11] = ldg8(p0l + tb + oa1 + 4); \
            bA[b][12] = ldg8(p1h + tb + oa1); bA[b][13] = ldg8(p1h + tb + oa1 + 4); \
            bA[b][14] = ldg8(p1l + tb + oa1); bA[b][15] = ldg8(p1l + tb + oa1 + 4); }
        WCHUNK(0); ISSUE_A(0, 0)
        WCHUNK(1); ISSUE_A(1, 1)

        // ---- x contribution + bias (VALU work covers A-load latency) ----
        float xc[8];
        {
            int r = tid >> 2, up = tid & 3;
            #pragma unroll
            for (int j = 0; j < 8; ++j) xc[j] = b0r[j];
            #pragma unroll
            for (int i = 0; i < 10; ++i) {
                float xv = xs[i * 64 + r];
                #pragma unroll
                for (int j = 0; j < 8; ++j)
                    xc[j] += xv * ldsWx[i * 32 + up * 8 + j];
            }
        }

        f32x4 C0[2], C1[2];
        #pragma unroll
        for (int rt = 0; rt < 2; ++rt) {
            C0[rt] = (f32x4){0.f, 0.f, 0.f, 0.f};
            C1[rt] = (f32x4){0.f, 0.f, 0.f, 0.f};
        }

        #pragma unroll
        for (int q = 0; q < 8; ++q) {
            const int b = q & 1;
            const int rbase = ch * 16 + l15;
            bf16x8 wah = bw[5 * ((0 * 8 + q) * 32 + rbase) + quad];  // hh0 hi
            bf16x8 wal = bw[5 * ((1 * 8 + q) * 32 + rbase) + quad];  // hh0 lo
            bf16x8 wbh = bw[5 * ((2 * 8 + q) * 32 + rbase) + quad];  // ih1 hi
            bf16x8 wbl = bw[5 * ((3 * 8 + q) * 32 + rbase) + quad];  // ih1 lo
            bf16x8 wch = bw[5 * ((4 * 8 + q) * 32 + rbase) + quad];  // hh1 hi
            bf16x8 wcl = bw[5 * ((5 * 8 + q) * 32 + rbase) + quad];  // hh1 lo
            FragU a0h, a0l, a1h, a1l;
            #pragma unroll
            for (int rt = 0; rt < 2; ++rt) {
                a0h.q[0] = bA[b][rt*8+0];  a0h.q[1] = bA[b][rt*8+1];
                a0l.q[0] = bA[b][rt*8+2];  a0l.q[1] = bA[b][rt*8+3];
                a1h.q[0] = bA[b][rt*8+4];  a1h.q[1] = bA[b][rt*8+5];
                a1l.q[0] = bA[b][rt*8+6];  a1l.q[1] = bA[b][rt*8+7];
                C0[rt] = __builtin_amdgcn_mfma_f32_16x16x32_bf16(a0h.v, wah, C0[rt], 0, 0, 0);
                C0[rt] = __builtin_amdgcn_mfma_f32_16x16x32_bf16(a0h.v, wal, C0[rt], 0, 0, 0);
                C0[rt] = __builtin_amdgcn_mfma_f32_16x16x32_bf16(a0l.v, wah, C0[rt], 0, 0, 0);
                C0[rt] = __builtin_amdgcn_mfma_f32_16x16x32_bf16(a0l.v, wal, C0[rt], 0, 0, 0);
                C1[rt] = __builtin_amdgcn_mfma_f32_16x16x32_bf16(a0h.v, wbh, C1[rt], 0, 0, 0);
                C1[rt] = __builtin_amdgcn_mfma_f32_16x16x32_bf16(a0h.v, wbl, C1[rt], 0, 0, 0);
                C1[rt] = __builtin_amdgcn_mfma_f32_16x16x32_bf16(a0l.v, wbh, C1[rt], 0, 0, 0);
                C1[rt] = __builtin_amdgcn_mfma_f32_16x16x32_bf16(a0l.v, wbl, C1[rt], 0, 0, 0);
                C1[rt] = __builtin_amdgcn_mfma_f32_16x16x32_bf16(a1h.v, wch, C1[rt], 0, 0, 0);
                C1[rt] = __builtin_amdgcn_mfma_f32_16x16x32_bf16(a1h.v, wcl, C1[rt], 0, 0, 0);
                C1[rt] = __builtin_amdgcn_mfma_f32_16x16x32_bf16(a1l.v, wch, C1[rt], 0, 0, 0);
                C1[rt] = __builtin_amdgcn_mfma_f32_16x16x32_bf16(a1l.v, wcl, C1[rt], 0, 0, 0);
            }
            if (q < 6) { WCHUNK(q + 2); ISSUE_A(b, q + 2) }
        }
        #undef ISSUE_A
        #undef WCHUNK

        // ---- C/D frags -> scratch (D: col=lane&15, row=quad*4+reg) ----
        #pragma unroll
        for (int rt = 0; rt < 2; ++rt)
            #pragma unroll
            for (int reg = 0; reg < 4; ++reg) {
                int rr = rh * 32 + rt * 16 + quad * 4 + reg;
                CS[rr * 33 + ch * 16 + l15]        = C0[rt][reg];
                CS[2112 + rr * 33 + ch * 16 + l15] = C1[rt][reg];
            }
        __syncthreads();

        // ---- eltwise (thread = row x unit-pair); pack + tile-contiguous store ----
        {
            int r = tid >> 2, up = tid & 3;
            if (e < TT) {
                float h0n[2];
                #pragma unroll
                for (int s = 0; s < 2; ++s) {
                    int c4 = up * 8 + s * 4;
                    float gi = CS[r * 33 + c4 + 0] + xc[s * 4 + 0];
                    float gf = CS[r * 33 + c4 + 1] + xc[s * 4 + 1];
                    float gg = CS[r * 33 + c4 + 2] + xc[s * 4 + 2];
                    float go = CS[r * 33 + c4 + 3] + xc[s * 4 + 3];
                    float cn = sigf(gf) * c0s[s] + sigf(gi) * tanhfast(gg);
                    c0s[s] = cn;
                    h0n[s] = sigf(go) * tanhfast(cn);
                }
                size_t tb = (size_t)((e & 1) * 8 + ib) * 16384 + (size_t)ik * 512 + 2 * tid;
                stg4(h0hi + tb, (u32)bhi(h0n[0]) | ((u32)bhi(h0n[1]) << 16));
                stg4(h0lo + tb, (u32)blo(h0n[0]) | ((u32)blo(h0n[1]) << 16));
            }
            if (e > 0) {
                float h1n[2];
                #pragma unroll
                for (int s = 0; s < 2; ++s) {
                    int c4 = up * 8 + s * 4;
                    float gi = CS[2112 + r * 33 + c4 + 0] + b1r[s * 4 + 0];
                    float gf = CS[2112 + r * 33 + c4 + 1] + b1r[s * 4 + 1];
                    float gg = CS[2112 + r * 33 + c4 + 2] + b1r[s * 4 + 2];
                    float go = CS[2112 + r * 33 + c4 + 3] + b1r[s * 4 + 3];
                    float cn = sigf(gf) * c1s[s] + sigf(gi) * tanhfast(gg);
                    c1s[s] = cn;
                    h1n[s] = sigf(go) * tanhfast(cn);
                }
                size_t tb = (size_t)(((e + 1) & 1) * 8 + ib) * 16384 + (size_t)ik * 512 + 2 * tid;
                stg4(h1hi + tb, (u32)bhi(h1n[0]) | ((u32)bhi(h1n[1]) << 16));
                stg4(h1lo + tb, (u32)blo(h1n[0]) | ((u32)blo(h1n[1]) << 16));
            }
        }
        asm volatile("s_waitcnt vmcnt(0)" ::: "memory");   // h stores at coherence pt
        __syncthreads();                                   // all threads' stores done
        if (tid == 0)
            __hip_atomic_store(flw, (u32)(e + 1),
                               __ATOMIC_RELAXED, __HIP_MEMORY_SCOPE_AGENT);
    }

    // ---- head: y[b] = h1[255] . Wlin + blin (slot 1, tile layout) ----
    if (ik == 0) {
        // wait for all 32 producers to finish step TT (flag value TT+1)
        u32 rdy = mkrdy(fl, lane, (u32)(TT + 1));
        while (rdy != 0xFFFFFFFFu) {
            __builtin_amdgcn_s_sleep(2);
            rdy = mkrdy(fl, lane, (u32)(TT + 1));
        }
        __builtin_amdgcn_sched_barrier(0);
        int r = tid >> 2, q4 = tid & 3;
        const unsigned short* ph = h1hi + (size_t)(1 * 8 + ib) * 16384;
        const unsigned short* pl = h1lo + (size_t)(1 * 8 + ib) * 16384;
        float sacc = 0.f;
        #pragma unroll 1
        for (int kk = 0; kk < 64; kk += 2) {
            int k = q4 * 64 + kk;
            int sa = (k >> 3) * 512 + r * 8 + (k & 7);
            u32 hw = ldg4(ph + sa), lwd = ldg4(pl + sa);
            sacc += (bff(hw & 0xFFFFu) + bff(lwd & 0xFFFFu)) * Wlin[k];
            sacc += (bff(hw >> 16)     + bff(lwd >> 16))     * Wlin[k + 1];
        }
        sacc += __shfl_down(sacc, 2, 4);
        sacc += __shfl_down(sacc, 1, 4);
        if (q4 == 0) out[rb0 + r] = sacc + blin[0];
    }
}

// ---------------------------------------------------------------------------
extern "C" void kernel_launch(void* const* d_in, const int* in_sizes, int n_in,
                              void* d_out, int out_size, void* d_ws, size_t ws_size,
                              hipStream_t stream) {
    const float* x     = (const float*)d_in[0];
    const float* W_ih0 = (const float*)d_in[1];
    const float* W_hh0 = (const float*)d_in[2];
    const float* b_ih0 = (const float*)d_in[3];
    const float* b_hh0 = (const float*)d_in[4];
    const float* W_ih1 = (const float*)d_in[5];
    const float* W_hh1 = (const float*)d_in[6];
    const float* b_ih1 = (const float*)d_in[7];
    const float* b_hh1 = (const float*)d_in[8];
    const float* W_lin = (const float*)d_in[9];
    const float* b_lin = (const float*)d_in[10];
    float* out = (float*)d_out;
    char* wsb  = (char*)d_ws;

    // zero h ring planes + flag region (ws re-poisoned before every timed launch)
    hipMemsetAsync(wsb + BOFF_H0HI, 0, 4 * 524288 + 131584, stream);

    split_w<<<3072, 256, 0, stream>>>(W_hh0, W_ih1, W_hh1,
                                      (unsigned short*)(wsb + BOFF_WT));
    transpose_gi<<<40, 256, 0, stream>>>(W_ih0, (float*)(wsb + BOFF_WX), 10);

    lstm_mfma<<<256, 256, 0, stream>>>(x, b_ih0, b_hh0, b_ih1, b_hh1,
                                       W_lin, b_lin, wsb, out);
}

// Round 5
// 1545.740 us; speedup vs baseline: 1.4178x; 1.3222x over previous
//
#include <hip/hip_runtime.h>
#include <math.h>

typedef unsigned int u32;
typedef unsigned long long u64;
typedef __attribute__((ext_vector_type(8))) short bf16x8;   // 8 bf16 = 4 VGPR
typedef __attribute__((ext_vector_type(4))) float f32x4;
typedef __attribute__((ext_vector_type(4))) int i32x4;

#define TT 256

// ---- ws byte offsets ----
#define BOFF_WT   0ULL          // bf16 [3 mat][2 pl][8 kc][1024 n][40 kpad] = 3,932,160 B
#define BOFF_WX   3932160ULL    // fp32 [10][1024] = 40,960 B
#define BOFF_H0HI 3973120ULL    // bf16 [2 slot][8 ib][32 ik][64 r][8 u] = 524,288 B each
#define BOFF_H0LO 4497408ULL
#define BOFF_H1HI 5021696ULL
#define BOFF_H1LO 5545984ULL
#define BOFF_FLG  6070272ULL    // flag region (fast sc0 lines + safe agent lines)

#define OB_H0HI 3973120u
#define OB_H0LO 4497408u
#define OB_H1HI 5021696u
#define OB_H1LO 5545984u
// fast flags (sc0, L2-resident): one 128B line per ib group, 32 u32 words
#define OB_FLGF 6070272u
// safe flags (agent scope): separate lines, +4096B
#define OB_FLGS 6074368u

// ---------------------------------------------------------------------------
// W [1024][K] row-major -> A [K][1024] gate-interleaved fp32 (for x-gemm)
__global__ void transpose_gi(const float* __restrict__ W, float* __restrict__ A, int K) {
    int idx = blockIdx.x * 256 + threadIdx.x;
    if (idx < K * 1024) {
        int kk = idx >> 10, r = idx & 1023, k = r >> 2, g = r & 3;
        A[idx] = W[(g * 256 + k) * K + kk];
    }
}

// Split fp32 weights into hi/lo bf16 planes, MFMA B-tile layout:
// wt[((mt*2+pl)*8 + kc)*1024 + n][40] , n = gate-col (u*4+g), k within chunk 0..31
__global__ void split_w(const float* __restrict__ W0, const float* __restrict__ W1,
                        const float* __restrict__ W2, unsigned short* __restrict__ wt) {
    int idx = blockIdx.x * 256 + threadIdx.x;      // 786432 total
    int k32 = idx & 31;
    int n   = (idx >> 5) & 1023;
    int kc  = (idx >> 15) & 7;
    int mt  = idx >> 18;
    const float* W = (mt == 0) ? W0 : (mt == 1) ? W1 : W2;
    int ug = n >> 2, g = n & 3, k = kc * 32 + k32;
    float v = W[(g * 256 + ug) * 256 + k];
    u32 b = __float_as_uint(v);
    unsigned short hi = (unsigned short)(b >> 16);               // truncated hi
    float lo = v - __uint_as_float(b & 0xFFFF0000u);             // exact residual
    u32 lb = __float_as_uint(lo);
    unsigned short los = (unsigned short)((lb + 0x7FFFu + ((lb >> 16) & 1u)) >> 16);
    wt[((size_t)((mt * 2 + 0) * 8 + kc) * 1024 + n) * 40 + k32] = hi;
    wt[((size_t)((mt * 2 + 1) * 8 + kc) * 1024 + n) * 40 + k32] = los;
}

__device__ __forceinline__ float sigf(float x)     { return 1.0f / (1.0f + __expf(-x)); }
__device__ __forceinline__ float tanhfast(float x) { return 1.0f - 2.0f / (__expf(2.0f * x) + 1.0f); }

__device__ __forceinline__ unsigned short bhi(float v) {
    return (unsigned short)(__float_as_uint(v) >> 16);
}
__device__ __forceinline__ unsigned short blo(float v) {
    float lo = v - __uint_as_float(__float_as_uint(v) & 0xFFFF0000u);
    u32 lb = __float_as_uint(lo);
    return (unsigned short)((lb + 0x7FFFu + ((lb >> 16) & 1u)) >> 16);
}
__device__ __forceinline__ float bff(u32 us) { return __uint_as_float(us << 16); }

// SRD over the whole workspace: stride 0, raw bytes, bounds off.
__device__ __forceinline__ i32x4 mksrd(const void* p) {
    u64 a = (u64)p;
    i32x4 r;
    r.x = (int)(u32)a;
    r.y = (int)((a >> 32) & 0xFFFFu);   // base hi16, stride=0
    r.z = (int)0xFFFFFFFFu;             // num_records: disable bounds
    r.w = 0x00020000;                   // raw dword access
    return r;
}

// Counted-vmcnt wait + scheduling fence (rule #18: MFMA must not hoist above).
#define WAITV(N) do { asm volatile("s_waitcnt vmcnt(" #N ")" ::: "memory"); \
                      __builtin_amdgcn_sched_barrier(0); } while (0)

// sc0 (L2-resident) ops: legal coherence point is the group's XCD L2.
__device__ __forceinline__ void ld16s(bf16x8& d, i32x4 rs, u32 voff) {
    asm volatile("buffer_load_dwordx4 %0, %1, %2, 0 offen sc0"
                 : "=v"(d) : "v"(voff), "s"(rs));
}
__device__ __forceinline__ void st4s(i32x4 rs, u32 voff, u32 v) {
    asm volatile("buffer_store_dword %0, %1, %2, 0 offen sc0"
                 :: "v"(v), "v"(voff), "s"(rs) : "memory");
}
__device__ __forceinline__ u32 ld4s(i32x4 rs, u32 voff) {
    u32 d;
    asm volatile("buffer_load_dword %0, %1, %2, 0 offen sc0"
                 : "=v"(d) : "v"(voff), "s"(rs) : "memory");
    return d;
}
// fast readiness snapshot: lane p reads fast-flag word p (sc0), ballot >= tgt
__device__ __forceinline__ u32 mkrdy_fast(i32x4 rs, u32 flB, int lane, u32 tgt) {
    u32 v;
    u32 off = flB + (u32)((lane & 31) * 4);
    asm volatile("buffer_load_dword %0, %1, %2, 0 offen sc0\n\t"
                 "s_waitcnt vmcnt(0)"
                 : "=v"(v) : "v"(off), "s"(rs) : "memory");
    unsigned long long b = __ballot(v >= tgt);
    return (u32)b;
}
// safe readiness snapshot: agent-scope flags (always visible, any XCD mapping)
__device__ __forceinline__ u32 mkrdy_safe(const u32* fl, int lane, u32 tgt) {
    u32 v = __hip_atomic_load(fl + (lane & 31), __ATOMIC_RELAXED,
                              __HIP_MEMORY_SCOPE_AGENT);
    unsigned long long b = __ballot(v >= tgt);
    return (u32)b;
}

// ---------------------------------------------------------------------------
// MFMA persistent 2-layer LSTM. 256 blocks (1/CU) x 256 threads (4 waves).
// Block (ib,ik): 64 batch rows x 8 hidden units (32 gate cols).
// NEW wave split: wave wv owns rows wv*16..+16, ALL 32 gate cols (2 B-tiles)
// -> no duplicated A-reads between waves (halves h-ring read traffic).
// h ring + flags are L2-resident via sc0 buffer ops (group ib = blockIdx%8
// expected XCD-uniform under round-robin dispatch; L2 is the coherence point).
// Dual-published flags: sc0 fast word + agent safe word; consumers poll fast
// with a bounded spin, then stick to safe (no hang if mapping assumption is
// wrong — absmax will flag it instead).
// ---------------------------------------------------------------------------
__global__ __launch_bounds__(256, 1)
void lstm_mfma(const float* __restrict__ x,
               const float* __restrict__ bih0, const float* __restrict__ bhh0,
               const float* __restrict__ bih1, const float* __restrict__ bhh1,
               const float* __restrict__ Wlin, const float* __restrict__ blin,
               char* __restrict__ wsb, float* __restrict__ out)
{
    __shared__ unsigned short lw[61440];   // B-tiles: [6 pl][8 kc][32 n][40 kpad]
    __shared__ float fsh[5184];            // Wx [10][32] | xs [10][64] | CS [2][64][33]
    float* ldsWx = fsh;
    float* xs    = fsh + 320;
    float* CS    = fsh + 960;

    const int tid  = threadIdx.x;
    const int lane = tid & 63;
    const int wv   = __builtin_amdgcn_readfirstlane(tid >> 6);
    const int quad = lane >> 4;
    const int l15  = lane & 15;
    const int ib   = blockIdx.x & 7;
    const int ik   = blockIdx.x >> 3;
    const int rb0  = ib * 64;

    i32x4 rs = mksrd(wsb);

    const unsigned short* wt = (const unsigned short*)(wsb + BOFF_WT);
    const float* gWx = (const float*)(wsb + BOFF_WX);
    const u32 flF  = OB_FLGF + (u32)(ib * 128);               // fast line (sc0)
    const u32* flS = (const u32*)(wsb + OB_FLGS) + ib * 32;   // safe line (agent)
    u32* flSw      = (u32*)(wsb + OB_FLGS) + ib * 32 + ik;

    // ---- one-time: weight B-tiles (this block's 32-col slice) into LDS ----
    #pragma unroll 1
    for (int j = 0; j < 30; ++j) {
        int i16 = tid + j * 256;               // 0..7679 (b128 units)
        int chk = i16 / 160;                   // plane-chunk 0..47
        int wi  = i16 - chk * 160;             // b128 unit within chunk
        size_t src = (size_t)chk * 40960 + (size_t)ik * 1280 + (size_t)wi * 8;
        *(ulonglong2*)(lw + (size_t)chk * 1280 + (size_t)wi * 8) =
            *(const ulonglong2*)(wt + src);
    }
    for (int n = tid; n < 320; n += 256)
        ldsWx[n] = gWx[(n >> 5) * 1024 + ik * 32 + (n & 31)];

    // biases in regs (eltwise mapping: r = tid>>2, unit-pair up = tid&3)
    float b0r[8], b1r[8];
    {
        int up = tid & 3;
        #pragma unroll
        for (int j = 0; j < 8; ++j) {
            int ul = up * 2 + (j >> 2), g = j & 3;
            int gi = g * 256 + ik * 8 + ul;
            b0r[j] = bih0[gi] + bhh0[gi];
            b1r[j] = bih1[gi] + bhh1[gi];
        }
    }
    float c0s[2] = {0.f, 0.f}, c1s[2] = {0.f, 0.f};
    const u32 oaB = (u32)(quad * 1024 + (wv * 16 + l15) * 16); // A-frag byte off
    const bf16x8* bw = (const bf16x8*)lw;
    int safeMode = 0;

    __syncthreads();

    for (int e = 0; e <= TT; ++e) {
        // ---- stage x[te] ----
        {
            int te = (e < TT) ? e : (TT - 1);
            #pragma unroll
            for (int rr = 0; rr < 2; ++rr) {
                int idx = tid + rr * 256;
                if (idx < 320) {
                    int r = idx / 5, j2 = idx - r * 5;
                    float2 v = *(const float2*)(x + (size_t)(rb0 + r) * 2560 + te * 10 + 2 * j2);
                    xs[(2 * j2) * 64 + r]     = v.x;
                    xs[(2 * j2 + 1) * 64 + r] = v.y;
                }
            }
        }
        __syncthreads();   // xs visible

        // ---- gate: all 32 producers at flag >= e (per-wave, dual-path) ----
        {
            const u32 tgt = (u32)e;
            u32 rdy;
            if (!safeMode) {
                rdy = mkrdy_fast(rs, flF, lane, tgt);
                int sp = 0;
                while (rdy != 0xFFFFFFFFu && ++sp < 4096)
                    rdy = mkrdy_fast(rs, flF, lane, tgt);
                if (rdy != 0xFFFFFFFFu) safeMode = 1;
            }
            if (safeMode) {
                rdy = mkrdy_safe(flS, lane, tgt);
                while (rdy != 0xFFFFFFFFu) {
                    __builtin_amdgcn_s_sleep(2);
                    rdy = mkrdy_safe(flS, lane, tgt);
                }
            }
            __builtin_amdgcn_sched_barrier(0);
        }
        WAITV(0);   // baseline: manual vmcnt counting starts at 0

        // ---- gemm: 8 k32-chunks; A sc0 from L2 h-ring, B from LDS ----
        const u32 vo0 = OB_H0HI + (u32)((((e + 1) & 1) * 8 + ib) * 32768);
        const u32 vo1 = OB_H0LO + (u32)((((e + 1) & 1) * 8 + ib) * 32768);
        const u32 vo2 = OB_H1HI + (u32)(((e & 1) * 8 + ib) * 32768);
        const u32 vo3 = OB_H1LO + (u32)(((e & 1) * 8 + ib) * 32768);

        bf16x8 fA[2][4];
        #define ISSUE(b, qc) { const u32 tB = (u32)((qc) * 4096) + oaB;   \
            ld16s(fA[b][0], rs, vo0 + tB);                                \
            ld16s(fA[b][1], rs, vo1 + tB);                                \
            ld16s(fA[b][2], rs, vo2 + tB);                                \
            ld16s(fA[b][3], rs, vo3 + tB); }
        ISSUE(0, 0)
        ISSUE(1, 1)

        // ---- x contribution + bias (VALU work covers first A-load latency) ----
        float xc[8];
        {
            int r = tid >> 2, up = tid & 3;
            #pragma unroll
            for (int j = 0; j < 8; ++j) xc[j] = b0r[j];
            #pragma unroll
            for (int i = 0; i < 10; ++i) {
                float xv = xs[i * 64 + r];
                #pragma unroll
                for (int j = 0; j < 8; ++j)
                    xc[j] += xv * ldsWx[i * 32 + up * 8 + j];
            }
        }

        f32x4 C0[2], C1[2];
        #pragma unroll
        for (int ct = 0; ct < 2; ++ct) {
            C0[ct] = (f32x4){0.f, 0.f, 0.f, 0.f};
            C1[ct] = (f32x4){0.f, 0.f, 0.f, 0.f};
        }

        #pragma unroll
        for (int q = 0; q < 8; ++q) {
            const int b = q & 1;
            bf16x8 wA[2][2], wB[2][2], wC[2][2];   // [hi/lo][col-tile]
            #pragma unroll
            for (int ct = 0; ct < 2; ++ct) {
                int rb = ct * 16 + l15;
                wA[0][ct] = bw[5 * ((0 * 8 + q) * 32 + rb) + quad];  // hh0 hi
                wA[1][ct] = bw[5 * ((1 * 8 + q) * 32 + rb) + quad];  // hh0 lo
                wB[0][ct] = bw[5 * ((2 * 8 + q) * 32 + rb) + quad];  // ih1 hi
                wB[1][ct] = bw[5 * ((3 * 8 + q) * 32 + rb) + quad];  // ih1 lo
                wC[0][ct] = bw[5 * ((4 * 8 + q) * 32 + rb) + quad];  // hh1 hi
                wC[1][ct] = bw[5 * ((5 * 8 + q) * 32 + rb) + quad];  // hh1 lo
            }
            // 2 chunks x 4 loads in flight; retire the oldest 4 (chunk q)
            if (q < 7) { WAITV(4); } else { WAITV(0); }
            bf16x8 a0h = fA[b][0], a0l = fA[b][1];
            bf16x8 a1h = fA[b][2], a1l = fA[b][3];
            #pragma unroll
            for (int ct = 0; ct < 2; ++ct) {
                C0[ct] = __builtin_amdgcn_mfma_f32_16x16x32_bf16(a0h, wA[0][ct], C0[ct], 0, 0, 0);
                C0[ct] = __builtin_amdgcn_mfma_f32_16x16x32_bf16(a0h, wA[1][ct], C0[ct], 0, 0, 0);
                C0[ct] = __builtin_amdgcn_mfma_f32_16x16x32_bf16(a0l, wA[0][ct], C0[ct], 0, 0, 0);
                C0[ct] = __builtin_amdgcn_mfma_f32_16x16x32_bf16(a0l, wA[1][ct], C0[ct], 0, 0, 0);
                C1[ct] = __builtin_amdgcn_mfma_f32_16x16x32_bf16(a0h, wB[0][ct], C1[ct], 0, 0, 0);
                C1[ct] = __builtin_amdgcn_mfma_f32_16x16x32_bf16(a0h, wB[1][ct], C1[ct], 0, 0, 0);
                C1[ct] = __builtin_amdgcn_mfma_f32_16x16x32_bf16(a0l, wB[0][ct], C1[ct], 0, 0, 0);
                C1[ct] = __builtin_amdgcn_mfma_f32_16x16x32_bf16(a0l, wB[1][ct], C1[ct], 0, 0, 0);
                C1[ct] = __builtin_amdgcn_mfma_f32_16x16x32_bf16(a1h, wC[0][ct], C1[ct], 0, 0, 0);
                C1[ct] = __builtin_amdgcn_mfma_f32_16x16x32_bf16(a1h, wC[1][ct], C1[ct], 0, 0, 0);
                C1[ct] = __builtin_amdgcn_mfma_f32_16x16x32_bf16(a1l, wC[0][ct], C1[ct], 0, 0, 0);
                C1[ct] = __builtin_amdgcn_mfma_f32_16x16x32_bf16(a1l, wC[1][ct], C1[ct], 0, 0, 0);
            }
            if (q < 6) ISSUE(b, q + 2)
        }
        #undef ISSUE

        // ---- C/D frags -> scratch (D: col=lane&15, row=quad*4+reg) ----
        #pragma unroll
        for (int ct = 0; ct < 2; ++ct)
            #pragma unroll
            for (int reg = 0; reg < 4; ++reg) {
                int rr = wv * 16 + quad * 4 + reg;
                CS[rr * 33 + ct * 16 + l15]        = C0[ct][reg];
                CS[2112 + rr * 33 + ct * 16 + l15] = C1[ct][reg];
            }
        __syncthreads();

        // ---- eltwise (thread = row x unit-pair); pack + sc0 store into L2 ----
        {
            int r = tid >> 2, up = tid & 3;
            if (e < TT) {
                float h0n[2];
                #pragma unroll
                for (int s = 0; s < 2; ++s) {
                    int c4 = up * 8 + s * 4;
                    float gi = CS[r * 33 + c4 + 0] + xc[s * 4 + 0];
                    float gf = CS[r * 33 + c4 + 1] + xc[s * 4 + 1];
                    float gg = CS[r * 33 + c4 + 2] + xc[s * 4 + 2];
                    float go = CS[r * 33 + c4 + 3] + xc[s * 4 + 3];
                    float cn = sigf(gf) * c0s[s] + sigf(gi) * tanhfast(gg);
                    c0s[s] = cn;
                    h0n[s] = sigf(go) * tanhfast(cn);
                }
                u32 sb = (u32)(((e & 1) * 8 + ib) * 32768 + ik * 1024 + 4 * tid);
                st4s(rs, OB_H0HI + sb, (u32)bhi(h0n[0]) | ((u32)bhi(h0n[1]) << 16));
                st4s(rs, OB_H0LO + sb, (u32)blo(h0n[0]) | ((u32)blo(h0n[1]) << 16));
            }
            if (e > 0) {
                float h1n[2];
                #pragma unroll
                for (int s = 0; s < 2; ++s) {
                    int c4 = up * 8 + s * 4;
                    float gi = CS[2112 + r * 33 + c4 + 0] + b1r[s * 4 + 0];
                    float gf = CS[2112 + r * 33 + c4 + 1] + b1r[s * 4 + 1];
                    float gg = CS[2112 + r * 33 + c4 + 2] + b1r[s * 4 + 2];
                    float go = CS[2112 + r * 33 + c4 + 3] + b1r[s * 4 + 3];
                    float cn = sigf(gf) * c1s[s] + sigf(gi) * tanhfast(gg);
                    c1s[s] = cn;
                    h1n[s] = sigf(go) * tanhfast(cn);
                }
                u32 sb = (u32)((((e + 1) & 1) * 8 + ib) * 32768 + ik * 1024 + 4 * tid);
                st4s(rs, OB_H1HI + sb, (u32)bhi(h1n[0]) | ((u32)bhi(h1n[1]) << 16));
                st4s(rs, OB_H1LO + sb, (u32)blo(h1n[0]) | ((u32)blo(h1n[1]) << 16));
            }
        }
        WAITV(0);          // h stores retired at L2 (coherence point)
        __syncthreads();   // all threads' stores done
        if (tid == 0) {
            st4s(rs, flF + (u32)(ik * 4), (u32)(e + 1));      // fast flag (sc0)
            __hip_atomic_store(flSw, (u32)(e + 1),
                               __ATOMIC_RELAXED, __HIP_MEMORY_SCOPE_AGENT);
        }
    }

    // ---- head: y[b] = h1[255] . Wlin + blin (slot 1, tile layout) ----
    if (ik == 0) {
        {
            const u32 tgt = (u32)(TT + 1);
            u32 rdy;
            if (!safeMode) {
                rdy = mkrdy_fast(rs, flF, lane, tgt);
                int sp = 0;
                while (rdy != 0xFFFFFFFFu && ++sp < 4096)
                    rdy = mkrdy_fast(rs, flF, lane, tgt);
                if (rdy != 0xFFFFFFFFu) safeMode = 1;
            }
            if (safeMode) {
                rdy = mkrdy_safe(flS, lane, tgt);
                while (rdy != 0xFFFFFFFFu) {
                    __builtin_amdgcn_s_sleep(2);
                    rdy = mkrdy_safe(flS, lane, tgt);
                }
            }
            __builtin_amdgcn_sched_barrier(0);
        }
        int r = tid >> 2, q4 = tid & 3;
        const u32 bh_ = OB_H1HI + (u32)((8 + ib) * 32768);
        const u32 bl_ = OB_H1LO + (u32)((8 + ib) * 32768);
        float sacc = 0.f;
        #pragma unroll 1
        for (int kk = 0; kk < 64; kk += 8) {
            u32 hw4[4], lw4[4];
            #pragma unroll
            for (int t = 0; t < 4; ++t) {
                int k = q4 * 64 + kk + 2 * t;
                u32 sa = (u32)(((k >> 3) * 512 + r * 8 + (k & 7)) * 2);
                hw4[t] = ld4s(rs, bh_ + sa);
                lw4[t] = ld4s(rs, bl_ + sa);
            }
            WAITV(0);
            #pragma unroll
            for (int t = 0; t < 4; ++t) {
                int k = q4 * 64 + kk + 2 * t;
                sacc += (bff(hw4[t] & 0xFFFFu) + bff(lw4[t] & 0xFFFFu)) * Wlin[k];
                sacc += (bff(hw4[t] >> 16)     + bff(lw4[t] >> 16))     * Wlin[k + 1];
            }
        }
        sacc += __shfl_down(sacc, 2, 4);
        sacc += __shfl_down(sacc, 1, 4);
        if (q4 == 0) out[rb0 + r] = sacc + blin[0];
    }
}

// ---------------------------------------------------------------------------
extern "C" void kernel_launch(void* const* d_in, const int* in_sizes, int n_in,
                              void* d_out, int out_size, void* d_ws, size_t ws_size,
                              hipStream_t stream) {
    const float* x     = (const float*)d_in[0];
    const float* W_ih0 = (const float*)d_in[1];
    const float* W_hh0 = (const float*)d_in[2];
    const float* b_ih0 = (const float*)d_in[3];
    const float* b_hh0 = (const float*)d_in[4];
    const float* W_ih1 = (const float*)d_in[5];
    const float* W_hh1 = (const float*)d_in[6];
    const float* b_ih1 = (const float*)d_in[7];
    const float* b_hh1 = (const float*)d_in[8];
    const float* W_lin = (const float*)d_in[9];
    const float* b_lin = (const float*)d_in[10];
    float* out = (float*)d_out;
    char* wsb  = (char*)d_ws;

    // zero h ring planes + flag region (ws re-poisoned before every timed launch)
    hipMemsetAsync(wsb + BOFF_H0HI, 0, 4 * 524288 + 131584, stream);

    split_w<<<3072, 256, 0, stream>>>(W_hh0, W_ih1, W_hh1,
                                      (unsigned short*)(wsb + BOFF_WT));
    transpose_gi<<<40, 256, 0, stream>>>(W_ih0, (float*)(wsb + BOFF_WX), 10);

    lstm_mfma<<<256, 256, 0, stream>>>(x, b_ih0, b_hh0, b_ih1, b_hh1,
                                       W_lin, b_lin, wsb, out);
}